// Round 1
// baseline (229.489 us; speedup 1.0000x reference)
//
#include <hip/hip_runtime.h>
#include <stdint.h>

// WaveletSparsityPrior: 3-level Haar, loss = sum_lvl w_lvl * sum min(|c|, t_lvl)
// Input: pred [128,1,512,512] fp32. Output: [loss, avg_noise] fp32.
//
// ws layout (floats):
//   [0,128)    spec_loss[b]   (loss assuming t=0.2 clip-top)
//   [128,256)  fix_loss[b]    (recomputed loss if t != 0.2)
//   [256,384)  sigma[b]
//   [384,512)  t[b]
//   [512, 512+128*12288)  |level-3 details| per batch (for median)

static constexpr int BATCH = 128;
static constexpr int W = 512;
static constexpr int N3 = 64 * 64;     // level-3 positions per batch
static constexpr int NDET = 3 * N3;    // 12288 detail coeffs per batch for median

__device__ __forceinline__ float block_reduce_sum(float v, float* lds) {
    #pragma unroll
    for (int off = 32; off > 0; off >>= 1)
        v += __shfl_down(v, off, 64);
    const int lane = threadIdx.x & 63;
    const int wave = threadIdx.x >> 6;
    if (lane == 0) lds[wave] = v;
    __syncthreads();
    if (threadIdx.x == 0) {
        float s = 0.0f;
        const int nw = blockDim.x >> 6;
        for (int w = 0; w < nw; ++w) s += lds[w];
        lds[0] = s;
    }
    __syncthreads();
    return lds[0];
}

// Computes, for one 8x8 input block: sum of min(|c|,t1) over 16 level-1 detail
// triples, min(|c|,t2) over 4 level-2 triples, min(|c|,t3) over 1 level-3
// triple. Optionally writes |level-3 details|.
__device__ __forceinline__ float wavelet_block_loss(
        const float* __restrict__ blk, float t1, float t2, float t3,
        float* detH, float* detV, float* detD, bool write_det) {
    float cA1[4][4];
    float s1 = 0.0f, s2 = 0.0f, s3 = 0.0f;

    #pragma unroll
    for (int rr = 0; rr < 4; ++rr) {
        const float4 r0a = *(const float4*)(blk + (size_t)(2 * rr) * W);
        const float4 r0b = *(const float4*)(blk + (size_t)(2 * rr) * W + 4);
        const float4 r1a = *(const float4*)(blk + (size_t)(2 * rr + 1) * W);
        const float4 r1b = *(const float4*)(blk + (size_t)(2 * rr + 1) * W + 4);
        const float top[8] = {r0a.x, r0a.y, r0a.z, r0a.w, r0b.x, r0b.y, r0b.z, r0b.w};
        const float bot[8] = {r1a.x, r1a.y, r1a.z, r1a.w, r1b.x, r1b.y, r1b.z, r1b.w};
        #pragma unroll
        for (int cc = 0; cc < 4; ++cc) {
            const float a = top[2 * cc], b = top[2 * cc + 1];
            const float c = bot[2 * cc], d = bot[2 * cc + 1];
            const float sab = a + b, scd = c + d, dab = a - b, dcd = c - d;
            const float cA = 0.5f * (sab + scd);
            const float cH = 0.5f * (sab - scd);
            const float cV = 0.5f * (dab + dcd);
            const float cD = 0.5f * (dab - dcd);
            s1 += fminf(fabsf(cH), t1) + fminf(fabsf(cV), t1) + fminf(fabsf(cD), t1);
            cA1[rr][cc] = cA;
        }
    }

    float cA2[2][2];
    #pragma unroll
    for (int rr = 0; rr < 2; ++rr) {
        #pragma unroll
        for (int cc = 0; cc < 2; ++cc) {
            const float a = cA1[2 * rr][2 * cc],     b = cA1[2 * rr][2 * cc + 1];
            const float c = cA1[2 * rr + 1][2 * cc], d = cA1[2 * rr + 1][2 * cc + 1];
            const float sab = a + b, scd = c + d, dab = a - b, dcd = c - d;
            const float cA = 0.5f * (sab + scd);
            const float cH = 0.5f * (sab - scd);
            const float cV = 0.5f * (dab + dcd);
            const float cD = 0.5f * (dab - dcd);
            s2 += fminf(fabsf(cH), t2) + fminf(fabsf(cV), t2) + fminf(fabsf(cD), t2);
            cA2[rr][cc] = cA;
        }
    }

    {
        const float a = cA2[0][0], b = cA2[0][1], c = cA2[1][0], d = cA2[1][1];
        const float sab = a + b, scd = c + d, dab = a - b, dcd = c - d;
        const float cH = 0.5f * (sab - scd);
        const float cV = 0.5f * (dab + dcd);
        const float cD = 0.5f * (dab - dcd);
        const float aH = fabsf(cH), aV = fabsf(cV), aD = fabsf(cD);
        s3 = fminf(aH, t3) + fminf(aV, t3) + fminf(aD, t3);
        if (write_det) { *detH = aH; *detV = aV; *detD = aD; }
    }

    // weights: level_idx=3 -> level-1 details (256x256), 1/3 * 1/3 / 65536
    //          level_idx=2 -> level-2 details (128x128), 1/2 * 1/3 / 16384
    //          level_idx=1 -> level-3 details (64x64),   1/1 * 1/3 / 4096
    const float w1 = 1.0f / (9.0f * 65536.0f);
    const float w2 = 1.0f / (6.0f * 16384.0f);
    const float w3 = 1.0f / (3.0f * 4096.0f);
    return s1 * w1 + s2 * w2 + s3 * w3;
}

// Pass A: speculative loss at t = clip-top (0.2) + write |level-3 details|.
__global__ __launch_bounds__(256) void pass_a(const float* __restrict__ x,
                                              float* __restrict__ spec_loss,
                                              float* __restrict__ det3) {
    const int b = blockIdx.y;
    const int p = blockIdx.x * 256 + threadIdx.x;   // level-3 position 0..4095
    const int i3 = p >> 6, j3 = p & 63;
    const float* blk = x + (size_t)b * W * W + (size_t)(i3 * 8) * W + j3 * 8;

    const float BASE = 40.0f / 400.0f;
    const float t3 = BASE * 2.0f, t2 = t3 * 0.5f, t1 = t3 * 0.25f;

    float* det = det3 + (size_t)b * NDET;
    const float part = wavelet_block_loss(blk, t1, t2, t3,
                                          &det[0 * N3 + p], &det[1 * N3 + p],
                                          &det[2 * N3 + p], true);
    __shared__ float lds[8];
    const float tot = block_reduce_sum(part, lds);
    if (threadIdx.x == 0) atomicAdd(&spec_loss[b], tot);
}

// Pass B: exact per-batch median of 12288 |details| via dual binary search on
// the uint32 bit patterns (monotone for non-negative floats).
__global__ __launch_bounds__(256) void pass_b(const float* __restrict__ det3,
                                              float* __restrict__ sigma_out,
                                              float* __restrict__ t_out) {
    const int b = blockIdx.x;
    const float* det = det3 + (size_t)b * NDET;

    uint32_t vals[48];
    #pragma unroll
    for (int i = 0; i < 48; ++i)
        vals[i] = __float_as_uint(det[threadIdx.x + 256 * i]);

    __shared__ uint32_t red[8];
    uint32_t lo1 = 0, hi1 = 0x7F800000u;   // order stat k=6143 (0-indexed)
    uint32_t lo2 = 0, hi2 = 0x7F800000u;   // order stat k=6144
    while (lo1 < hi1 || lo2 < hi2) {
        const uint32_t mid1 = (lo1 + hi1) >> 1;
        const uint32_t mid2 = (lo2 + hi2) >> 1;
        uint32_t c1 = 0, c2 = 0;
        #pragma unroll
        for (int i = 0; i < 48; ++i) {
            c1 += (vals[i] <= mid1);
            c2 += (vals[i] <= mid2);
        }
        uint32_t packed = c1 | (c2 << 16);
        #pragma unroll
        for (int off = 32; off > 0; off >>= 1)
            packed += __shfl_down(packed, off, 64);
        const int lane = threadIdx.x & 63, wave = threadIdx.x >> 6;
        if (lane == 0) red[wave] = packed;
        __syncthreads();
        if (threadIdx.x == 0) red[0] = red[0] + red[1] + red[2] + red[3];
        __syncthreads();
        packed = red[0];
        __syncthreads();   // protect red[] before next iteration's writes
        c1 = packed & 0xFFFFu;
        c2 = packed >> 16;
        if (lo1 < hi1) { if (c1 >= 6144u) hi1 = mid1; else lo1 = mid1 + 1; }
        if (lo2 < hi2) { if (c2 >= 6145u) hi2 = mid2; else lo2 = mid2 + 1; }
    }

    if (threadIdx.x == 0) {
        const float v1 = __uint_as_float(lo1);
        const float v2 = __uint_as_float(lo2);
        const float med = 0.5f * (v1 + v2);
        const float M2S = (float)(1.0 / 0.6745);
        const float sig = med * M2S;
        sigma_out[b] = sig;
        const float BASE = 40.0f / 400.0f;
        t_out[b] = fminf(fmaxf(sig * 2.5f, BASE * 0.5f), BASE * 2.0f);
    }
}

// Pass C: correction — recompute batches whose t did NOT clip to the top.
// For N(0,1)-scale inputs this early-exits everywhere (t == 0.2 exactly).
__global__ __launch_bounds__(256) void pass_c(const float* __restrict__ x,
                                              const float* __restrict__ t_in,
                                              float* __restrict__ fix_loss) {
    const int b = blockIdx.y;
    const float BASE = 40.0f / 400.0f;
    const float t = t_in[b];
    if (t == BASE * 2.0f) return;   // speculative pass already correct

    const int p = blockIdx.x * 256 + threadIdx.x;
    const int i3 = p >> 6, j3 = p & 63;
    const float* blk = x + (size_t)b * W * W + (size_t)(i3 * 8) * W + j3 * 8;

    const float part = wavelet_block_loss(blk, t * 0.25f, t * 0.5f, t,
                                          nullptr, nullptr, nullptr, false);
    __shared__ float lds[8];
    const float tot = block_reduce_sum(part, lds);
    if (threadIdx.x == 0) atomicAdd(&fix_loss[b], tot);
}

__global__ __launch_bounds__(128) void finalize(const float* __restrict__ spec,
                                                const float* __restrict__ fix,
                                                const float* __restrict__ sigma,
                                                const float* __restrict__ t_in,
                                                float* __restrict__ out) {
    __shared__ float lds[8];
    const float BASE = 40.0f / 400.0f;
    const int i = threadIdx.x;   // 128 threads, one per batch
    const float lb = (t_in[i] == BASE * 2.0f) ? spec[i] : fix[i];
    const float sg = sigma[i];
    const float ls = block_reduce_sum(lb, lds);
    __syncthreads();
    const float ss = block_reduce_sum(sg, lds);
    if (threadIdx.x == 0) {
        out[0] = ls * (1.0f / 128.0f);
        out[1] = ss * (1.0f / 128.0f);
    }
}

extern "C" void kernel_launch(void* const* d_in, const int* in_sizes, int n_in,
                              void* d_out, int out_size, void* d_ws, size_t ws_size,
                              hipStream_t stream) {
    const float* x = (const float*)d_in[0];
    float* ws = (float*)d_ws;
    float* spec  = ws;
    float* fix   = ws + 128;
    float* sigma = ws + 256;
    float* t     = ws + 384;
    float* det3  = ws + 512;   // 128 * 12288 floats = 6.3 MB

    hipMemsetAsync(spec, 0, 256 * sizeof(float), stream);  // spec + fix

    dim3 grid(16, BATCH);
    pass_a<<<grid, 256, 0, stream>>>(x, spec, det3);
    pass_b<<<BATCH, 256, 0, stream>>>(det3, sigma, t);
    pass_c<<<grid, 256, 0, stream>>>(x, t, fix);
    finalize<<<1, 128, 0, stream>>>(spec, fix, sigma, t, (float*)d_out);
}